// Round 15
// baseline (374.490 us; speedup 1.0000x reference)
//
#include <hip/hip_runtime.h>
#include <stdint.h>

#define E_ 8
#define DIN 256
#define DOUT 256
#define HID 512
#define GHID 128
#define NTOK 32768
#define NROW (NTOK * 2)
#define TABCAP 520
#define CNT_STRIDE 32

typedef float f32x4 __attribute__((ext_vector_type(4)));
typedef short bf16x8 __attribute__((ext_vector_type(8)));

// fp32 -> bf16 round-to-nearest-even
__device__ __forceinline__ unsigned short f2bf(float f) {
    unsigned int u = __float_as_uint(f);
    u += 0x7FFFu + ((u >> 16) & 1u);
    return (unsigned short)(u >> 16);
}

// async global->LDS, 16B per lane; LDS base must be wave-uniform (HW adds lane*16)
__device__ __forceinline__ void gload_lds16(const void* g, void* l) {
    __builtin_amdgcn_global_load_lds(
        (const __attribute__((address_space(1))) unsigned int*)g,
        (__attribute__((address_space(3))) unsigned int*)l, 16, 0, 0);
}

// ---------- weight transpose + bf16 convert: W[e][K][N] -> WT[e][N][K] ----------
__global__ __launch_bounds__(256) void k_transpose_bf16(
    const float* __restrict__ src, unsigned short* __restrict__ dst, int K, int N) {
    __shared__ float tile[64][65];
    int e = blockIdx.z;
    int k0 = blockIdx.x * 64, n0 = blockIdx.y * 64;
    const float* s = src + (size_t)e * K * N;
    unsigned short* d = dst + (size_t)e * N * K;
    int col = threadIdx.x & 63, ri = threadIdx.x >> 6;
#pragma unroll
    for (int it = 0; it < 16; ++it) {
        int row = it * 4 + ri;
        tile[row][col] = s[(size_t)(k0 + row) * N + n0 + col];
    }
    __syncthreads();
#pragma unroll
    for (int it = 0; it < 16; ++it) {
        int nrow = it * 4 + ri;
        d[(size_t)(n0 + nrow) * K + k0 + col] = f2bf(tile[col][nrow]);
    }
}

// ---------- fused gate: h = relu(x@gW1+gb1) in regs -> LDS; logits/top2 in-block ----------
__global__ __launch_bounds__(256) void k_gate(
    const float* __restrict__ x, const float* __restrict__ gW1,
    const float* __restrict__ gb1, const float* __restrict__ gW2,
    const float* __restrict__ gb2, int2* __restrict__ tokE,
    float2* __restrict__ tokW, int* __restrict__ cnt) {
    __shared__ float xT[32][132];   // [kk][tok]
    __shared__ float ws[32][132];   // [kk][hid]
    __shared__ float hs[128][132];  // h tile fp32 (67.6 KB)
    __shared__ float wg[GHID * E_]; // gW2 4 KB
    __shared__ int lcnt[E_];
    int t = threadIdx.x;
    int tokBase = blockIdx.x * 128;
    int tx = t & 15, ty = t >> 4;
    float acc[8][8];
#pragma unroll
    for (int i = 0; i < 8; ++i)
#pragma unroll
        for (int j = 0; j < 8; ++j) acc[i][j] = 0.f;

#pragma unroll
    for (int i = 0; i < 4; ++i) wg[i * 256 + t] = gW2[i * 256 + t];
    if (t < E_) lcnt[t] = 0;

    int stok = t >> 1;
    int skh = (t & 1) * 16;
    int wkk = t >> 3;
    int wh = (t & 7) * 16;

    for (int k0 = 0; k0 < DIN; k0 += 32) {
        const float* xr = x + (size_t)(tokBase + stok) * DIN + k0 + skh;
        float4 a0 = ((const float4*)xr)[0];
        float4 a1 = ((const float4*)xr)[1];
        float4 a2 = ((const float4*)xr)[2];
        float4 a3 = ((const float4*)xr)[3];
        xT[skh + 0][stok] = a0.x;  xT[skh + 1][stok] = a0.y;
        xT[skh + 2][stok] = a0.z;  xT[skh + 3][stok] = a0.w;
        xT[skh + 4][stok] = a1.x;  xT[skh + 5][stok] = a1.y;
        xT[skh + 6][stok] = a1.z;  xT[skh + 7][stok] = a1.w;
        xT[skh + 8][stok] = a2.x;  xT[skh + 9][stok] = a2.y;
        xT[skh + 10][stok] = a2.z; xT[skh + 11][stok] = a2.w;
        xT[skh + 12][stok] = a3.x; xT[skh + 13][stok] = a3.y;
        xT[skh + 14][stok] = a3.z; xT[skh + 15][stok] = a3.w;
        const float* wr = gW1 + (size_t)(k0 + wkk) * GHID + wh;
        *(float4*)&ws[wkk][wh + 0]  = ((const float4*)wr)[0];
        *(float4*)&ws[wkk][wh + 4]  = ((const float4*)wr)[1];
        *(float4*)&ws[wkk][wh + 8]  = ((const float4*)wr)[2];
        *(float4*)&ws[wkk][wh + 12] = ((const float4*)wr)[3];
        __syncthreads();
#pragma unroll 4
        for (int kk = 0; kk < 32; ++kk) {
            f32x4 wv0 = *(const f32x4*)&ws[kk][tx * 8];
            f32x4 wv1 = *(const f32x4*)&ws[kk][tx * 8 + 4];
            f32x4 xv0 = *(const f32x4*)&xT[kk][ty * 8];
            f32x4 xv1 = *(const f32x4*)&xT[kk][ty * 8 + 4];
            float xs[8] = {xv0.x, xv0.y, xv0.z, xv0.w, xv1.x, xv1.y, xv1.z, xv1.w};
            float wsv[8] = {wv0.x, wv0.y, wv0.z, wv0.w, wv1.x, wv1.y, wv1.z, wv1.w};
#pragma unroll
            for (int i = 0; i < 8; ++i)
#pragma unroll
                for (int j = 0; j < 8; ++j) acc[i][j] += xs[i] * wsv[j];
        }
        __syncthreads();
    }
    float4 b0 = *(const float4*)&gb1[tx * 8];
    float4 b1 = *(const float4*)&gb1[tx * 8 + 4];
#pragma unroll
    for (int i = 0; i < 8; ++i) {
        int trow = ty * 8 + i;
        float4 o0, o1;
        o0.x = fmaxf(acc[i][0] + b0.x, 0.f); o0.y = fmaxf(acc[i][1] + b0.y, 0.f);
        o0.z = fmaxf(acc[i][2] + b0.z, 0.f); o0.w = fmaxf(acc[i][3] + b0.w, 0.f);
        o1.x = fmaxf(acc[i][4] + b1.x, 0.f); o1.y = fmaxf(acc[i][5] + b1.y, 0.f);
        o1.z = fmaxf(acc[i][6] + b1.z, 0.f); o1.w = fmaxf(acc[i][7] + b1.w, 0.f);
        *(float4*)&hs[trow][tx * 8] = o0;
        *(float4*)&hs[trow][tx * 8 + 4] = o1;
    }
    __syncthreads();

    // phase 2: logits + top2. 2 lanes per token, 64 hid each.
    int tok = t >> 1, part = t & 1;
    float s[8];
#pragma unroll
    for (int e = 0; e < E_; ++e) s[e] = 0.f;
    const float* hr = &hs[tok][part * 64];
#pragma unroll 4
    for (int jq = 0; jq < 16; ++jq) {
        f32x4 hv = *(const f32x4*)&hr[jq * 4];
#pragma unroll
        for (int j = 0; j < 4; ++j) {
            float h = hv[j];
            int hidx = part * 64 + jq * 4 + j;
            f32x4 w0 = *(const f32x4*)&wg[hidx * 8];
            f32x4 w1 = *(const f32x4*)&wg[hidx * 8 + 4];
            s[0] += h * w0.x; s[1] += h * w0.y; s[2] += h * w0.z; s[3] += h * w0.w;
            s[4] += h * w1.x; s[5] += h * w1.y; s[6] += h * w1.z; s[7] += h * w1.w;
        }
    }
#pragma unroll
    for (int e = 0; e < E_; ++e) s[e] += __shfl_xor(s[e], 1);
    if (part == 0) {
        float l[8];
#pragma unroll
        for (int e = 0; e < E_; ++e) l[e] = s[e] + gb2[e];
        int i1 = 0; float b1v = l[0];
#pragma unroll
        for (int e = 1; e < E_; ++e) if (l[e] > b1v) { b1v = l[e]; i1 = e; }
        int i2 = -1; float b2v = -3.4e38f;
#pragma unroll
        for (int e = 0; e < E_; ++e) if (e != i1 && l[e] > b2v) { b2v = l[e]; i2 = e; }
        float mm = fmaxf(b1v, b2v);
        float p1 = expf(b1v - mm), p2 = expf(b2v - mm);
        float inv = 1.f / (p1 + p2);
        int gtok = tokBase + tok;
        tokE[gtok] = make_int2(i1, i2);
        tokW[gtok] = make_float2(p1 * inv, p2 * inv);
        atomicAdd(&lcnt[i1], 1);
        atomicAdd(&lcnt[i2], 1);
    }
    __syncthreads();
    if (t < E_) atomicAdd(&cnt[t * CNT_STRIDE], lcnt[t]);
}

// ---------- prefix offsets, tile work table, aux outputs (parallel fill) ----------
__global__ void k_route_setup(const int* __restrict__ cnt, int* __restrict__ offs,
                              int* __restrict__ fill, int2* __restrict__ tab,
                              int* __restrict__ NT, float* __restrict__ outTail) {
    int t = threadIdx.x;   // 64 threads
    int c[E_], nt[E_];
#pragma unroll
    for (int e = 0; e < E_; ++e) {
        c[e] = cnt[e * CNT_STRIDE];
        nt[e] = (c[e] + 127) >> 7;
    }
    if (t == 0) {
        int off = 0, ntp = 0;
        float bl = 0.f;
#pragma unroll
        for (int e = 0; e < E_; ++e) {
            offs[e] = off; off += c[e];
            fill[e] = 0;
            ntp += nt[e];
            float u = (float)c[e] / 32768.f;
            outTail[8388609 + e] = u;
            float dd = u - 0.125f;
            bl += dd * dd;
        }
        outTail[8388608] = bl * (0.01f / 8.f);
        *NT = ntp;
    }
    int maxnt = 0;
#pragma unroll
    for (int e = 0; e < E_; ++e) maxnt = max(maxnt, nt[e]);
    for (int k = t; k < maxnt; k += 64) {
        int p = 0;
#pragma unroll
        for (int e = 0; e < E_; ++e) p += min(nt[e], k);
#pragma unroll
        for (int e = 0; e < E_; ++e) {
            if (k < nt[e]) {
                tab[p] = make_int2(e, k);
                ++p;
            }
        }
    }
}

// ---------- gather: assign rows, record token/weight + tokRow, copy x to bf16 ----------
__global__ __launch_bounds__(256) void k_gather(
    const float* __restrict__ x, const int2* __restrict__ tokE,
    const float2* __restrict__ tokW, const int* __restrict__ offs,
    int* __restrict__ fill, int* __restrict__ rowTok, float* __restrict__ rowW,
    int2* __restrict__ tokRow, unsigned short* __restrict__ xg) {
    __shared__ int lc[E_], lbase[E_], lfill[E_];
    __shared__ int srow[512];
    int t = threadIdx.x;
    int tokBase = blockIdx.x * 256;
    if (t < E_) { lc[t] = 0; lfill[t] = 0; }
    __syncthreads();
    for (int s = t; s < 512; s += 256) {
        int token = tokBase + (s >> 1);
        int2 ee = tokE[token];
        int e = (s & 1) ? ee.y : ee.x;
        atomicAdd(&lc[e], 1);
    }
    __syncthreads();
    if (t < E_) lbase[t] = atomicAdd(&fill[t], lc[t]);
    __syncthreads();
    for (int s = t; s < 512; s += 256) {
        int token = tokBase + (s >> 1);
        int2 ee = tokE[token];
        float2 wv = tokW[token];
        int e; float w;
        if (s & 1) { e = ee.y; w = wv.y; } else { e = ee.x; w = wv.x; }
        int r = atomicAdd(&lfill[e], 1);
        int row = offs[e] + lbase[e] + r;
        srow[s] = row;
        rowTok[row] = token;
        rowW[row] = w;
        ((int*)&tokRow[token])[s & 1] = row;
    }
    __syncthreads();
    int wid = t >> 6, lane = t & 63;
    for (int s = wid; s < 512; s += 4) {
        int row = srow[s];
        int token = tokBase + (s >> 1);
        float4 v = ((const float4*)x)[(size_t)token * 64 + lane];
        ushort4 o;
        o.x = f2bf(v.x); o.y = f2bf(v.y); o.z = f2bf(v.z); o.w = f2bf(v.w);
        ((ushort4*)xg)[(size_t)row * 64 + lane] = o;
    }
}

// ---------- grouped GEMM, 128x128 tile, 8 waves, BK=32, 4-buf counted-vmcnt ----------
// R14's 48KB LDS rounds to 64KB (occ 50% = 2 blocks/CU) -> the 4th buffer is
// occupancy-FREE. Depth-3 prefetch: steady-state 6 loads outstanding, wait
// vmcnt(4) drains stage(s) leaving s+1/s+2 in flight (~3 compute phases + 3
// barriers for each stage to land). Tail: vmcnt(2) then vmcnt(0).
// Safety: stage(s+3) overwrites buf[(s+3)&3] = buf[s-1]; all reads of buf[s-1]
// happened in iter s-1 and are lgkmcnt-retired before this iter's barrier.
// LDS chunk-XOR swizzle (conflicts=0). XCD remap pins experts to XCDs.
// mode 0: Hout = relu(acc+bias) bf16
// mode 1: outF[row][col] = acc + bias (plain fp32 store; combine applies weights)
template <int NCT>
__global__ __launch_bounds__(512, 4) void k_gemm(
    const unsigned short* __restrict__ A, const unsigned short* __restrict__ BT,
    const float* __restrict__ bias, const int* __restrict__ offs,
    const int* __restrict__ cnt, const int2* __restrict__ tab,
    const int* __restrict__ NT, int N, int K, int mode,
    unsigned short* __restrict__ Hout, float* __restrict__ outF,
    const int* __restrict__ rowTok, const float* __restrict__ rowW) {
    __shared__ __align__(16) unsigned short As[4][128 * 32];  // 4 x 8 KB
    __shared__ __align__(16) unsigned short Bs[4][128 * 32];  // 4 x 8 KB

    unsigned flat = blockIdx.x + (unsigned)NCT * blockIdx.y;
    unsigned xcd = flat % 8u;
    unsigned q = flat / 8u;
    unsigned ct = q % (unsigned)NCT;
    unsigned tIdx = (q / (unsigned)NCT) * 8u + xcd;

    if (tIdx >= (unsigned)*NT || tIdx >= (unsigned)TABCAP) return;
    int2 ent = tab[tIdx];
    int e = ent.x, rt = ent.y;
    int cntE = cnt[e * CNT_STRIDE];
    int rowStart = offs[e] + rt * 128;
    int valid = cntE - rt * 128;
    if (valid > 128) valid = 128;

    int t = threadIdx.x;
    int lane = t & 63, wid = t >> 6;          // 8 waves
    int quad = lane >> 4, l15 = lane & 15;
    int waveM = wid >> 2, waveN = wid & 3;    // 2M x 4N: wave owns 64 rows x 32 cols

    const unsigned short* Ablk = A + (size_t)rowStart * K;
    const unsigned short* Bblk = BT + ((size_t)e * N + (size_t)ct * 128) * K;

    int srow = t >> 2, skc = t & 3;
    int skcs = skc ^ ((srow >> 1) & 3);
    int ar = min(srow, valid - 1);
    const unsigned short* ga = Ablk + (size_t)ar * K + skcs * 8;
    const unsigned short* gb = Bblk + (size_t)srow * K + skcs * 8;
    int la = wid * 512;

    auto stage = [&](int b, int kt) {
        gload_lds16(ga + kt, &As[b][la]);
        gload_lds16(gb + kt, &Bs[b][la]);
    };

    const f32x4 zero = {0.f, 0.f, 0.f, 0.f};
    f32x4 acc[4][2];
#pragma unroll
    for (int i = 0; i < 4; ++i)
#pragma unroll
        for (int j = 0; j < 2; ++j) acc[i][j] = zero;

    int xq = quad ^ ((l15 >> 1) & 3);   // swizzled read chunk
    int nst = K >> 5;                    // 8 or 16 (always >= 3)
    stage(0, 0);
    stage(1, 32);
    stage(2, 64);
    for (int s = 0; s < nst; ++s) {
        if (s + 3 <= nst) {
            asm volatile("s_waitcnt vmcnt(4)" ::: "memory");  // drain stage(s); s+1,s+2 in flight
        } else if (s + 2 == nst) {
            asm volatile("s_waitcnt vmcnt(2)" ::: "memory");  // drain stage(s); s+1 in flight
        } else {
            asm volatile("s_waitcnt vmcnt(0)" ::: "memory");  // last step
        }
        __builtin_amdgcn_s_barrier();
        asm volatile("" ::: "memory");   // fence: no ds_read hoists above barrier
        if (s + 3 < nst) stage((s + 3) & 3, (s + 3) << 5);
        const unsigned short* Ab = As[s & 3];
        const unsigned short* Bb = Bs[s & 3];
        bf16x8 af[4], bf[2];
#pragma unroll
        for (int i = 0; i < 4; ++i)
            af[i] = *(const bf16x8*)&Ab[(waveM * 64 + i * 16 + l15) * 32 + xq * 8];
#pragma unroll
        for (int j = 0; j < 2; ++j)
            bf[j] = *(const bf16x8*)&Bb[(waveN * 32 + j * 16 + l15) * 32 + xq * 8];
#pragma unroll
        for (int i = 0; i < 4; ++i)
#pragma unroll
            for (int j = 0; j < 2; ++j)
                acc[i][j] = __builtin_amdgcn_mfma_f32_16x16x32_bf16(af[i], bf[j], acc[i][j], 0, 0, 0);
    }

    const float* be = bias + (size_t)e * N;
    if (mode == 0) {
#pragma unroll
        for (int i = 0; i < 4; ++i) {
#pragma unroll
            for (int r = 0; r < 4; ++r) {
                int rl = waveM * 64 + i * 16 + quad * 4 + r;
                if (rl < valid) {
                    size_t rowOff = (size_t)(rowStart + rl) * N;
#pragma unroll
                    for (int j = 0; j < 2; ++j) {
                        int col = (int)ct * 128 + waveN * 32 + j * 16 + l15;
                        float v = acc[i][j][r] + be[col];
                        Hout[rowOff + col] = f2bf(fmaxf(v, 0.f));
                    }
                }
            }
        }
    } else {
#pragma unroll
        for (int i = 0; i < 4; ++i) {
#pragma unroll
            for (int r = 0; r < 4; ++r) {
                int rl = waveM * 64 + i * 16 + quad * 4 + r;
                if (rl < valid) {
                    float* yrow = outF + (size_t)(rowStart + rl) * N;
#pragma unroll
                    for (int j = 0; j < 2; ++j) {
                        int col = (int)ct * 128 + waveN * 32 + j * 16 + l15;
                        yrow[col] = acc[i][j][r] + be[col];
                    }
                }
            }
        }
    }
}

// ---------- combine: out[tok] = w0*y[row0] + w1*y[row1] ----------
__global__ __launch_bounds__(256) void k_combine(
    const float* __restrict__ y, const int2* __restrict__ tokRow,
    const float* __restrict__ rowW, float* __restrict__ out) {
    int gid = blockIdx.x * 256 + threadIdx.x;   // one float4 per thread
    int tok = gid >> 6;                          // 64 threads per token
    int cg = (gid & 63) << 2;
    int2 rr = tokRow[tok];
    float w0 = rowW[rr.x], w1 = rowW[rr.y];
    float4 a = *(const float4*)&y[(size_t)rr.x * DOUT + cg];
    float4 b = *(const float4*)&y[(size_t)rr.y * DOUT + cg];
    float4 o;
    o.x = w0 * a.x + w1 * b.x;
    o.y = w0 * a.y + w1 * b.y;
    o.z = w0 * a.z + w1 * b.z;
    o.w = w0 * a.w + w1 * b.w;
    *(float4*)&out[(size_t)tok * DOUT + cg] = o;
}

extern "C" void kernel_launch(void* const* d_in, const int* in_sizes, int n_in,
                              void* d_out, int out_size, void* d_ws, size_t ws_size,
                              hipStream_t stream) {
    const float* x   = (const float*)d_in[0];
    const float* gW1 = (const float*)d_in[1];
    const float* gb1 = (const float*)d_in[2];
    const float* gW2 = (const float*)d_in[3];
    const float* gb2 = (const float*)d_in[4];
    const float* We1 = (const float*)d_in[5];
    const float* be1 = (const float*)d_in[6];
    const float* We2 = (const float*)d_in[7];
    const float* be2 = (const float*)d_in[8];
    const float* We3 = (const float*)d_in[9];
    const float* be3 = (const float*)d_in[10];
    float* out = (float*)d_out;

    uint8_t* ws = (uint8_t*)d_ws;
    size_t off = 0;
    auto alloc = [&](size_t bytes) -> void* {
        void* p = ws + off;
        off += (bytes + 255) & ~(size_t)255;
        return p;
    };
    unsigned short* WT1 = (unsigned short*)alloc((size_t)E_ * HID * DIN * 2);   // [E][512][256]
    unsigned short* WT2 = (unsigned short*)alloc((size_t)E_ * HID * HID * 2);   // [E][512][512]
    unsigned short* WT3 = (unsigned short*)alloc((size_t)E_ * DOUT * HID * 2);  // [E][256][512]
    unsigned short* R1  = (unsigned short*)alloc((size_t)NROW * HID * 2);       // xg then h2
    unsigned short* h1  = (unsigned short*)alloc((size_t)NROW * HID * 2);       // h1 then y (fp32)
    int2*   tokE   = (int2*)alloc((size_t)NTOK * 8);
    float2* tokW   = (float2*)alloc((size_t)NTOK * 8);
    int*    rowTok = (int*)alloc((size_t)NROW * 4);
    float*  rowW   = (float*)alloc((size_t)NROW * 4);
    int2*   tokRow = (int2*)alloc((size_t)NTOK * 8);
    int*    cnt    = (int*)alloc(E_ * CNT_STRIDE * 4);
    int*    offs   = (int*)alloc(256);
    int*    fill   = (int*)alloc(256);
    int*    NT     = (int*)alloc(256);
    int2*   tab    = (int2*)alloc(TABCAP * 8);
    unsigned short* xg = R1;   // [NROW][256] bf16 (dead after gemm1)
    unsigned short* h2 = R1;   // [NROW][512] bf16 (written by gemm2)
    float* y = (float*)h1;     // [NROW][256] fp32 (h1 dead after gemm2)

    hipMemsetAsync(cnt, 0, E_ * CNT_STRIDE * 4, stream);

    k_transpose_bf16<<<dim3(DIN / 64, HID / 64, E_), 256, 0, stream>>>(We1, WT1, DIN, HID);
    k_transpose_bf16<<<dim3(HID / 64, HID / 64, E_), 256, 0, stream>>>(We2, WT2, HID, HID);
    k_transpose_bf16<<<dim3(HID / 64, DOUT / 64, E_), 256, 0, stream>>>(We3, WT3, HID, DOUT);

    k_gate<<<NTOK / 128, 256, 0, stream>>>(x, gW1, gb1, gW2, gb2, tokE, tokW, cnt);
    k_route_setup<<<1, 64, 0, stream>>>(cnt, offs, fill, tab, NT, out);
    k_gather<<<NTOK / 256, 256, 0, stream>>>(x, tokE, tokW, offs, fill, rowTok, rowW,
                                             tokRow, xg);

    k_gemm<4><<<dim3(4, TABCAP), 512, 0, stream>>>(xg, WT1, be1, offs, cnt, tab, NT,
                                                   HID, DIN, 0, h1, nullptr, rowTok, rowW);
    k_gemm<4><<<dim3(4, TABCAP), 512, 0, stream>>>(h1, WT2, be2, offs, cnt, tab, NT,
                                                   HID, HID, 0, h2, nullptr, rowTok, rowW);
    k_gemm<2><<<dim3(2, TABCAP), 512, 0, stream>>>(h2, WT3, be3, offs, cnt, tab, NT,
                                                   DOUT, HID, 1, nullptr, y, rowTok, rowW);
    k_combine<<<NTOK * DOUT / 4 / 256, 256, 0, stream>>>(y, tokRow, rowW, out);
}

// Round 16
// 340.892 us; speedup vs baseline: 1.0986x; 1.0986x over previous
//
#include <hip/hip_runtime.h>
#include <stdint.h>

#define E_ 8
#define DIN 256
#define DOUT 256
#define HID 512
#define GHID 128
#define NTOK 32768
#define NROW (NTOK * 2)
#define TABCAP 520
#define CNT_STRIDE 32

typedef float f32x4 __attribute__((ext_vector_type(4)));
typedef short bf16x8 __attribute__((ext_vector_type(8)));

// fp32 -> bf16 round-to-nearest-even
__device__ __forceinline__ unsigned short f2bf(float f) {
    unsigned int u = __float_as_uint(f);
    u += 0x7FFFu + ((u >> 16) & 1u);
    return (unsigned short)(u >> 16);
}

// async global->LDS, 16B per lane; LDS base must be wave-uniform (HW adds lane*16)
__device__ __forceinline__ void gload_lds16(const void* g, void* l) {
    __builtin_amdgcn_global_load_lds(
        (const __attribute__((address_space(1))) unsigned int*)g,
        (__attribute__((address_space(3))) unsigned int*)l, 16, 0, 0);
}

// ---------- merged weight transpose + bf16 convert: W[e][K][N] -> WT[e][N][K] ----------
// One launch for all three weights. Flat block id decodes region:
//   [0,256):   We1 (K=256,N=512) tiles 4x8 per e
//   [256,768): We2 (K=512,N=512) tiles 8x8 per e
//   [768,1024): We3 (K=512,N=256) tiles 8x4 per e
__global__ __launch_bounds__(256) void k_transpose_all(
    const float* __restrict__ We1, const float* __restrict__ We2,
    const float* __restrict__ We3, unsigned short* __restrict__ WT1,
    unsigned short* __restrict__ WT2, unsigned short* __restrict__ WT3) {
    __shared__ float tile[64][65];
    int b = blockIdx.x;
    const float* src; unsigned short* dst; int K, N, e, kt, nt;
    if (b < 256) {
        K = DIN; N = HID; src = We1; dst = WT1;
        e = b >> 5; int r = b & 31; kt = r >> 3; nt = r & 7;       // 4x8 tiles
    } else if (b < 768) {
        K = HID; N = HID; src = We2; dst = WT2;
        int bb = b - 256; e = bb >> 6; int r = bb & 63; kt = r >> 3; nt = r & 7;  // 8x8
    } else {
        K = HID; N = DOUT; src = We3; dst = WT3;
        int bb = b - 768; e = bb >> 5; int r = bb & 31; kt = r >> 2; nt = r & 3;  // 8x4
    }
    int k0 = kt * 64, n0 = nt * 64;
    const float* s = src + (size_t)e * K * N;
    unsigned short* d = dst + (size_t)e * N * K;
    int col = threadIdx.x & 63, ri = threadIdx.x >> 6;
#pragma unroll
    for (int it = 0; it < 16; ++it) {
        int row = it * 4 + ri;
        tile[row][col] = s[(size_t)(k0 + row) * N + n0 + col];
    }
    __syncthreads();
#pragma unroll
    for (int it = 0; it < 16; ++it) {
        int nrow = it * 4 + ri;
        d[(size_t)(n0 + nrow) * K + k0 + col] = f2bf(tile[col][nrow]);
    }
}

// ---------- fused gate: h = relu(x@gW1+gb1) in regs -> LDS; logits/top2 in-block ----------
__global__ __launch_bounds__(256) void k_gate(
    const float* __restrict__ x, const float* __restrict__ gW1,
    const float* __restrict__ gb1, const float* __restrict__ gW2,
    const float* __restrict__ gb2, int2* __restrict__ tokE,
    float2* __restrict__ tokW, int* __restrict__ cnt) {
    __shared__ float xT[32][132];   // [kk][tok]
    __shared__ float ws[32][132];   // [kk][hid]
    __shared__ float hs[128][132];  // h tile fp32 (67.6 KB)
    __shared__ float wg[GHID * E_]; // gW2 4 KB
    __shared__ int lcnt[E_];
    int t = threadIdx.x;
    int tokBase = blockIdx.x * 128;
    int tx = t & 15, ty = t >> 4;
    float acc[8][8];
#pragma unroll
    for (int i = 0; i < 8; ++i)
#pragma unroll
        for (int j = 0; j < 8; ++j) acc[i][j] = 0.f;

#pragma unroll
    for (int i = 0; i < 4; ++i) wg[i * 256 + t] = gW2[i * 256 + t];
    if (t < E_) lcnt[t] = 0;

    int stok = t >> 1;
    int skh = (t & 1) * 16;
    int wkk = t >> 3;
    int wh = (t & 7) * 16;

    for (int k0 = 0; k0 < DIN; k0 += 32) {
        const float* xr = x + (size_t)(tokBase + stok) * DIN + k0 + skh;
        float4 a0 = ((const float4*)xr)[0];
        float4 a1 = ((const float4*)xr)[1];
        float4 a2 = ((const float4*)xr)[2];
        float4 a3 = ((const float4*)xr)[3];
        xT[skh + 0][stok] = a0.x;  xT[skh + 1][stok] = a0.y;
        xT[skh + 2][stok] = a0.z;  xT[skh + 3][stok] = a0.w;
        xT[skh + 4][stok] = a1.x;  xT[skh + 5][stok] = a1.y;
        xT[skh + 6][stok] = a1.z;  xT[skh + 7][stok] = a1.w;
        xT[skh + 8][stok] = a2.x;  xT[skh + 9][stok] = a2.y;
        xT[skh + 10][stok] = a2.z; xT[skh + 11][stok] = a2.w;
        xT[skh + 12][stok] = a3.x; xT[skh + 13][stok] = a3.y;
        xT[skh + 14][stok] = a3.z; xT[skh + 15][stok] = a3.w;
        const float* wr = gW1 + (size_t)(k0 + wkk) * GHID + wh;
        *(float4*)&ws[wkk][wh + 0]  = ((const float4*)wr)[0];
        *(float4*)&ws[wkk][wh + 4]  = ((const float4*)wr)[1];
        *(float4*)&ws[wkk][wh + 8]  = ((const float4*)wr)[2];
        *(float4*)&ws[wkk][wh + 12] = ((const float4*)wr)[3];
        __syncthreads();
#pragma unroll 4
        for (int kk = 0; kk < 32; ++kk) {
            f32x4 wv0 = *(const f32x4*)&ws[kk][tx * 8];
            f32x4 wv1 = *(const f32x4*)&ws[kk][tx * 8 + 4];
            f32x4 xv0 = *(const f32x4*)&xT[kk][ty * 8];
            f32x4 xv1 = *(const f32x4*)&xT[kk][ty * 8 + 4];
            float xs[8] = {xv0.x, xv0.y, xv0.z, xv0.w, xv1.x, xv1.y, xv1.z, xv1.w};
            float wsv[8] = {wv0.x, wv0.y, wv0.z, wv0.w, wv1.x, wv1.y, wv1.z, wv1.w};
#pragma unroll
            for (int i = 0; i < 8; ++i)
#pragma unroll
                for (int j = 0; j < 8; ++j) acc[i][j] += xs[i] * wsv[j];
        }
        __syncthreads();
    }
    float4 b0 = *(const float4*)&gb1[tx * 8];
    float4 b1 = *(const float4*)&gb1[tx * 8 + 4];
#pragma unroll
    for (int i = 0; i < 8; ++i) {
        int trow = ty * 8 + i;
        float4 o0, o1;
        o0.x = fmaxf(acc[i][0] + b0.x, 0.f); o0.y = fmaxf(acc[i][1] + b0.y, 0.f);
        o0.z = fmaxf(acc[i][2] + b0.z, 0.f); o0.w = fmaxf(acc[i][3] + b0.w, 0.f);
        o1.x = fmaxf(acc[i][4] + b1.x, 0.f); o1.y = fmaxf(acc[i][5] + b1.y, 0.f);
        o1.z = fmaxf(acc[i][6] + b1.z, 0.f); o1.w = fmaxf(acc[i][7] + b1.w, 0.f);
        *(float4*)&hs[trow][tx * 8] = o0;
        *(float4*)&hs[trow][tx * 8 + 4] = o1;
    }
    __syncthreads();

    // phase 2: logits + top2. 2 lanes per token, 64 hid each.
    int tok = t >> 1, part = t & 1;
    float s[8];
#pragma unroll
    for (int e = 0; e < E_; ++e) s[e] = 0.f;
    const float* hr = &hs[tok][part * 64];
#pragma unroll 4
    for (int jq = 0; jq < 16; ++jq) {
        f32x4 hv = *(const f32x4*)&hr[jq * 4];
#pragma unroll
        for (int j = 0; j < 4; ++j) {
            float h = hv[j];
            int hidx = part * 64 + jq * 4 + j;
            f32x4 w0 = *(const f32x4*)&wg[hidx * 8];
            f32x4 w1 = *(const f32x4*)&wg[hidx * 8 + 4];
            s[0] += h * w0.x; s[1] += h * w0.y; s[2] += h * w0.z; s[3] += h * w0.w;
            s[4] += h * w1.x; s[5] += h * w1.y; s[6] += h * w1.z; s[7] += h * w1.w;
        }
    }
#pragma unroll
    for (int e = 0; e < E_; ++e) s[e] += __shfl_xor(s[e], 1);
    if (part == 0) {
        float l[8];
#pragma unroll
        for (int e = 0; e < E_; ++e) l[e] = s[e] + gb2[e];
        int i1 = 0; float b1v = l[0];
#pragma unroll
        for (int e = 1; e < E_; ++e) if (l[e] > b1v) { b1v = l[e]; i1 = e; }
        int i2 = -1; float b2v = -3.4e38f;
#pragma unroll
        for (int e = 0; e < E_; ++e) if (e != i1 && l[e] > b2v) { b2v = l[e]; i2 = e; }
        float mm = fmaxf(b1v, b2v);
        float p1 = expf(b1v - mm), p2 = expf(b2v - mm);
        float inv = 1.f / (p1 + p2);
        int gtok = tokBase + tok;
        tokE[gtok] = make_int2(i1, i2);
        tokW[gtok] = make_float2(p1 * inv, p2 * inv);
        atomicAdd(&lcnt[i1], 1);
        atomicAdd(&lcnt[i2], 1);
    }
    __syncthreads();
    if (t < E_) atomicAdd(&cnt[t * CNT_STRIDE], lcnt[t]);
}

// ---------- prefix offsets, tile work table, aux outputs (parallel fill) ----------
__global__ void k_route_setup(const int* __restrict__ cnt, int* __restrict__ offs,
                              int* __restrict__ fill, int2* __restrict__ tab,
                              int* __restrict__ NT, float* __restrict__ outTail) {
    int t = threadIdx.x;   // 64 threads
    int c[E_], nt[E_];
#pragma unroll
    for (int e = 0; e < E_; ++e) {
        c[e] = cnt[e * CNT_STRIDE];
        nt[e] = (c[e] + 127) >> 7;
    }
    if (t == 0) {
        int off = 0, ntp = 0;
        float bl = 0.f;
#pragma unroll
        for (int e = 0; e < E_; ++e) {
            offs[e] = off; off += c[e];
            fill[e] = 0;
            ntp += nt[e];
            float u = (float)c[e] / 32768.f;
            outTail[8388609 + e] = u;
            float dd = u - 0.125f;
            bl += dd * dd;
        }
        outTail[8388608] = bl * (0.01f / 8.f);
        *NT = ntp;
    }
    int maxnt = 0;
#pragma unroll
    for (int e = 0; e < E_; ++e) maxnt = max(maxnt, nt[e]);
    for (int k = t; k < maxnt; k += 64) {
        int p = 0;
#pragma unroll
        for (int e = 0; e < E_; ++e) p += min(nt[e], k);
#pragma unroll
        for (int e = 0; e < E_; ++e) {
            if (k < nt[e]) {
                tab[p] = make_int2(e, k);
                ++p;
            }
        }
    }
}

// ---------- gather: assign rows, record token/weight + tokRow, copy x to bf16 ----------
__global__ __launch_bounds__(256) void k_gather(
    const float* __restrict__ x, const int2* __restrict__ tokE,
    const float2* __restrict__ tokW, const int* __restrict__ offs,
    int* __restrict__ fill, int* __restrict__ rowTok, float* __restrict__ rowW,
    int2* __restrict__ tokRow, unsigned short* __restrict__ xg) {
    __shared__ int lc[E_], lbase[E_], lfill[E_];
    __shared__ int srow[512];
    int t = threadIdx.x;
    int tokBase = blockIdx.x * 256;
    if (t < E_) { lc[t] = 0; lfill[t] = 0; }
    __syncthreads();
    for (int s = t; s < 512; s += 256) {
        int token = tokBase + (s >> 1);
        int2 ee = tokE[token];
        int e = (s & 1) ? ee.y : ee.x;
        atomicAdd(&lc[e], 1);
    }
    __syncthreads();
    if (t < E_) lbase[t] = atomicAdd(&fill[t], lc[t]);
    __syncthreads();
    for (int s = t; s < 512; s += 256) {
        int token = tokBase + (s >> 1);
        int2 ee = tokE[token];
        float2 wv = tokW[token];
        int e; float w;
        if (s & 1) { e = ee.y; w = wv.y; } else { e = ee.x; w = wv.x; }
        int r = atomicAdd(&lfill[e], 1);
        int row = offs[e] + lbase[e] + r;
        srow[s] = row;
        rowTok[row] = token;
        rowW[row] = w;
        ((int*)&tokRow[token])[s & 1] = row;
    }
    __syncthreads();
    int wid = t >> 6, lane = t & 63;
    for (int s = wid; s < 512; s += 4) {
        int row = srow[s];
        int token = tokBase + (s >> 1);
        float4 v = ((const float4*)x)[(size_t)token * 64 + lane];
        ushort4 o;
        o.x = f2bf(v.x); o.y = f2bf(v.y); o.z = f2bf(v.z); o.w = f2bf(v.w);
        ((ushort4*)xg)[(size_t)row * 64 + lane] = o;
    }
}

// ---------- grouped GEMM, 128x128 tile, 8 waves, BK=32, 3-buf counted-vmcnt ----------
// R14-verified config (gemm2 62us, occ 50%, conflicts 0). T4 counted vmcnt:
// 3 LDS buffers (48KB), prefetch 2 ahead, steady-state s_waitcnt vmcnt(2)
// -> s_barrier -> stage(s+2) -> ds_read -> MFMA.
// LDS chunk-XOR swizzle (conflicts=0). XCD remap pins experts to XCDs.
// mode 0: Hout = relu(acc+bias) bf16
// mode 1: outF[row][col] = acc + bias (plain fp32 store; combine applies weights)
template <int NCT>
__global__ __launch_bounds__(512, 4) void k_gemm(
    const unsigned short* __restrict__ A, const unsigned short* __restrict__ BT,
    const float* __restrict__ bias, const int* __restrict__ offs,
    const int* __restrict__ cnt, const int2* __restrict__ tab,
    const int* __restrict__ NT, int N, int K, int mode,
    unsigned short* __restrict__ Hout, float* __restrict__ outF,
    const int* __restrict__ rowTok, const float* __restrict__ rowW) {
    __shared__ __align__(16) unsigned short As[3][128 * 32];  // 3 x 8 KB
    __shared__ __align__(16) unsigned short Bs[3][128 * 32];  // 3 x 8 KB

    unsigned flat = blockIdx.x + (unsigned)NCT * blockIdx.y;
    unsigned xcd = flat % 8u;
    unsigned q = flat / 8u;
    unsigned ct = q % (unsigned)NCT;
    unsigned tIdx = (q / (unsigned)NCT) * 8u + xcd;

    if (tIdx >= (unsigned)*NT || tIdx >= (unsigned)TABCAP) return;
    int2 ent = tab[tIdx];
    int e = ent.x, rt = ent.y;
    int cntE = cnt[e * CNT_STRIDE];
    int rowStart = offs[e] + rt * 128;
    int valid = cntE - rt * 128;
    if (valid > 128) valid = 128;

    int t = threadIdx.x;
    int lane = t & 63, wid = t >> 6;          // 8 waves
    int quad = lane >> 4, l15 = lane & 15;
    int waveM = wid >> 2, waveN = wid & 3;    // 2M x 4N: wave owns 64 rows x 32 cols

    const unsigned short* Ablk = A + (size_t)rowStart * K;
    const unsigned short* Bblk = BT + ((size_t)e * N + (size_t)ct * 128) * K;

    int srow = t >> 2, skc = t & 3;
    int skcs = skc ^ ((srow >> 1) & 3);
    int ar = min(srow, valid - 1);
    const unsigned short* ga = Ablk + (size_t)ar * K + skcs * 8;
    const unsigned short* gb = Bblk + (size_t)srow * K + skcs * 8;
    int la = wid * 512;

    auto stage = [&](int b, int kt) {
        gload_lds16(ga + kt, &As[b][la]);
        gload_lds16(gb + kt, &Bs[b][la]);
    };

    const f32x4 zero = {0.f, 0.f, 0.f, 0.f};
    f32x4 acc[4][2];
#pragma unroll
    for (int i = 0; i < 4; ++i)
#pragma unroll
        for (int j = 0; j < 2; ++j) acc[i][j] = zero;

    int xq = quad ^ ((l15 >> 1) & 3);   // swizzled read chunk
    int nst = K >> 5;                    // 8 or 16
    stage(0, 0);
    stage(1, 32);
    int bs = 0;
    for (int s = 0; s < nst; ++s) {
        if (s + 1 < nst) {
            asm volatile("s_waitcnt vmcnt(2)" ::: "memory");
        } else {
            asm volatile("s_waitcnt vmcnt(0)" ::: "memory");
        }
        __builtin_amdgcn_s_barrier();
        asm volatile("" ::: "memory");
        if (s + 2 < nst) {
            int b2 = bs + 2; if (b2 >= 3) b2 -= 3;
            stage(b2, (s + 2) << 5);
        }
        const unsigned short* Ab = As[bs];
        const unsigned short* Bb = Bs[bs];
        bf16x8 af[4], bf[2];
#pragma unroll
        for (int i = 0; i < 4; ++i)
            af[i] = *(const bf16x8*)&Ab[(waveM * 64 + i * 16 + l15) * 32 + xq * 8];
#pragma unroll
        for (int j = 0; j < 2; ++j)
            bf[j] = *(const bf16x8*)&Bb[(waveN * 32 + j * 16 + l15) * 32 + xq * 8];
#pragma unroll
        for (int i = 0; i < 4; ++i)
#pragma unroll
            for (int j = 0; j < 2; ++j)
                acc[i][j] = __builtin_amdgcn_mfma_f32_16x16x32_bf16(af[i], bf[j], acc[i][j], 0, 0, 0);
        ++bs; if (bs == 3) bs = 0;
    }

    const float* be = bias + (size_t)e * N;
    if (mode == 0) {
#pragma unroll
        for (int i = 0; i < 4; ++i) {
#pragma unroll
            for (int r = 0; r < 4; ++r) {
                int rl = waveM * 64 + i * 16 + quad * 4 + r;
                if (rl < valid) {
                    size_t rowOff = (size_t)(rowStart + rl) * N;
#pragma unroll
                    for (int j = 0; j < 2; ++j) {
                        int col = (int)ct * 128 + waveN * 32 + j * 16 + l15;
                        float v = acc[i][j][r] + be[col];
                        Hout[rowOff + col] = f2bf(fmaxf(v, 0.f));
                    }
                }
            }
        }
    } else {
#pragma unroll
        for (int i = 0; i < 4; ++i) {
#pragma unroll
            for (int r = 0; r < 4; ++r) {
                int rl = waveM * 64 + i * 16 + quad * 4 + r;
                if (rl < valid) {
                    float* yrow = outF + (size_t)(rowStart + rl) * N;
#pragma unroll
                    for (int j = 0; j < 2; ++j) {
                        int col = (int)ct * 128 + waveN * 32 + j * 16 + l15;
                        yrow[col] = acc[i][j][r] + be[col];
                    }
                }
            }
        }
    }
}

// ---------- combine: out[tok] = w0*y[row0] + w1*y[row1] ----------
__global__ __launch_bounds__(256) void k_combine(
    const float* __restrict__ y, const int2* __restrict__ tokRow,
    const float* __restrict__ rowW, float* __restrict__ out) {
    int gid = blockIdx.x * 256 + threadIdx.x;   // one float4 per thread
    int tok = gid >> 6;                          // 64 threads per token
    int cg = (gid & 63) << 2;
    int2 rr = tokRow[tok];
    float w0 = rowW[rr.x], w1 = rowW[rr.y];
    float4 a = *(const float4*)&y[(size_t)rr.x * DOUT + cg];
    float4 b = *(const float4*)&y[(size_t)rr.y * DOUT + cg];
    float4 o;
    o.x = w0 * a.x + w1 * b.x;
    o.y = w0 * a.y + w1 * b.y;
    o.z = w0 * a.z + w1 * b.z;
    o.w = w0 * a.w + w1 * b.w;
    *(float4*)&out[(size_t)tok * DOUT + cg] = o;
}

extern "C" void kernel_launch(void* const* d_in, const int* in_sizes, int n_in,
                              void* d_out, int out_size, void* d_ws, size_t ws_size,
                              hipStream_t stream) {
    const float* x   = (const float*)d_in[0];
    const float* gW1 = (const float*)d_in[1];
    const float* gb1 = (const float*)d_in[2];
    const float* gW2 = (const float*)d_in[3];
    const float* gb2 = (const float*)d_in[4];
    const float* We1 = (const float*)d_in[5];
    const float* be1 = (const float*)d_in[6];
    const float* We2 = (const float*)d_in[7];
    const float* be2 = (const float*)d_in[8];
    const float* We3 = (const float*)d_in[9];
    const float* be3 = (const float*)d_in[10];
    float* out = (float*)d_out;

    uint8_t* ws = (uint8_t*)d_ws;
    size_t off = 0;
    auto alloc = [&](size_t bytes) -> void* {
        void* p = ws + off;
        off += (bytes + 255) & ~(size_t)255;
        return p;
    };
    unsigned short* WT1 = (unsigned short*)alloc((size_t)E_ * HID * DIN * 2);   // [E][512][256]
    unsigned short* WT2 = (unsigned short*)alloc((size_t)E_ * HID * HID * 2);   // [E][512][512]
    unsigned short* WT3 = (unsigned short*)alloc((size_t)E_ * DOUT * HID * 2);  // [E][256][512]
    unsigned short* R1  = (unsigned short*)alloc((size_t)NROW * HID * 2);       // xg then h2
    unsigned short* h1  = (unsigned short*)alloc((size_t)NROW * HID * 2);       // h1 then y (fp32)
    int2*   tokE   = (int2*)alloc((size_t)NTOK * 8);
    float2* tokW   = (float2*)alloc((size_t)NTOK * 8);
    int*    rowTok = (int*)alloc((size_t)NROW * 4);
    float*  rowW   = (float*)alloc((size_t)NROW * 4);
    int2*   tokRow = (int2*)alloc((size_t)NTOK * 8);
    int*    cnt    = (int*)alloc(E_ * CNT_STRIDE * 4);
    int*    offs   = (int*)alloc(256);
    int*    fill   = (int*)alloc(256);
    int*    NT     = (int*)alloc(256);
    int2*   tab    = (int2*)alloc(TABCAP * 8);
    unsigned short* xg = R1;   // [NROW][256] bf16 (dead after gemm1)
    unsigned short* h2 = R1;   // [NROW][512] bf16 (written by gemm2)
    float* y = (float*)h1;     // [NROW][256] fp32 (h1 dead after gemm2)

    hipMemsetAsync(cnt, 0, E_ * CNT_STRIDE * 4, stream);

    k_transpose_all<<<1024, 256, 0, stream>>>(We1, We2, We3, WT1, WT2, WT3);

    k_gate<<<NTOK / 128, 256, 0, stream>>>(x, gW1, gb1, gW2, gb2, tokE, tokW, cnt);
    k_route_setup<<<1, 64, 0, stream>>>(cnt, offs, fill, tab, NT, out);
    k_gather<<<NTOK / 256, 256, 0, stream>>>(x, tokE, tokW, offs, fill, rowTok, rowW,
                                             tokRow, xg);

    k_gemm<4><<<dim3(4, TABCAP), 512, 0, stream>>>(xg, WT1, be1, offs, cnt, tab, NT,
                                                   HID, DIN, 0, h1, nullptr, rowTok, rowW);
    k_gemm<4><<<dim3(4, TABCAP), 512, 0, stream>>>(h1, WT2, be2, offs, cnt, tab, NT,
                                                   HID, HID, 0, h2, nullptr, rowTok, rowW);
    k_gemm<2><<<dim3(2, TABCAP), 512, 0, stream>>>(h2, WT3, be3, offs, cnt, tab, NT,
                                                   DOUT, HID, 1, nullptr, y, rowTok, rowW);
    k_combine<<<NTOK * DOUT / 4 / 256, 256, 0, stream>>>(y, tokRow, rowW, out);
}

// Round 18
// 339.296 us; speedup vs baseline: 1.1037x; 1.0047x over previous
//
#include <hip/hip_runtime.h>
#include <stdint.h>

#define E_ 8
#define DIN 256
#define DOUT 256
#define HID 512
#define GHID 128
#define NTOK 32768
#define NROW (NTOK * 2)
#define TABCAP 520
#define CNT_STRIDE 32

typedef float f32x4 __attribute__((ext_vector_type(4)));
typedef short bf16x8 __attribute__((ext_vector_type(8)));

// fp32 -> bf16 round-to-nearest-even
__device__ __forceinline__ unsigned short f2bf(float f) {
    unsigned int u = __float_as_uint(f);
    u += 0x7FFFu + ((u >> 16) & 1u);
    return (unsigned short)(u >> 16);
}

// async global->LDS, 16B per lane; LDS base must be wave-uniform (HW adds lane*16)
__device__ __forceinline__ void gload_lds16(const void* g, void* l) {
    __builtin_amdgcn_global_load_lds(
        (const __attribute__((address_space(1))) unsigned int*)g,
        (__attribute__((address_space(3))) unsigned int*)l, 16, 0, 0);
}

// ---------- merged weight transpose + bf16 convert: W[e][K][N] -> WT[e][N][K] ----------
// One launch for all three weights. Flat block id decodes region:
//   [0,256):   We1 (K=256,N=512) tiles 4x8 per e
//   [256,768): We2 (K=512,N=512) tiles 8x8 per e
//   [768,1024): We3 (K=512,N=256) tiles 8x4 per e
__global__ __launch_bounds__(256) void k_transpose_all(
    const float* __restrict__ We1, const float* __restrict__ We2,
    const float* __restrict__ We3, unsigned short* __restrict__ WT1,
    unsigned short* __restrict__ WT2, unsigned short* __restrict__ WT3) {
    __shared__ float tile[64][65];
    int b = blockIdx.x;
    const float* src; unsigned short* dst; int K, N, e, kt, nt;
    if (b < 256) {
        K = DIN; N = HID; src = We1; dst = WT1;
        e = b >> 5; int r = b & 31; kt = r >> 3; nt = r & 7;       // 4x8 tiles
    } else if (b < 768) {
        K = HID; N = HID; src = We2; dst = WT2;
        int bb = b - 256; e = bb >> 6; int r = bb & 63; kt = r >> 3; nt = r & 7;  // 8x8
    } else {
        K = HID; N = DOUT; src = We3; dst = WT3;
        int bb = b - 768; e = bb >> 5; int r = bb & 31; kt = r >> 2; nt = r & 3;  // 8x4
    }
    int k0 = kt * 64, n0 = nt * 64;
    const float* s = src + (size_t)e * K * N;
    unsigned short* d = dst + (size_t)e * N * K;
    int col = threadIdx.x & 63, ri = threadIdx.x >> 6;
#pragma unroll
    for (int it = 0; it < 16; ++it) {
        int row = it * 4 + ri;
        tile[row][col] = s[(size_t)(k0 + row) * N + n0 + col];
    }
    __syncthreads();
#pragma unroll
    for (int it = 0; it < 16; ++it) {
        int nrow = it * 4 + ri;
        d[(size_t)(n0 + nrow) * K + k0 + col] = f2bf(tile[col][nrow]);
    }
}

// ---------- fused gate: h = relu(x@gW1+gb1) in regs -> LDS; logits/top2 in-block ----------
__global__ __launch_bounds__(256) void k_gate(
    const float* __restrict__ x, const float* __restrict__ gW1,
    const float* __restrict__ gb1, const float* __restrict__ gW2,
    const float* __restrict__ gb2, int2* __restrict__ tokE,
    float2* __restrict__ tokW, int* __restrict__ cnt) {
    __shared__ float xT[32][132];   // [kk][tok]
    __shared__ float ws[32][132];   // [kk][hid]
    __shared__ float hs[128][132];  // h tile fp32 (67.6 KB)
    __shared__ float wg[GHID * E_]; // gW2 4 KB
    __shared__ int lcnt[E_];
    int t = threadIdx.x;
    int tokBase = blockIdx.x * 128;
    int tx = t & 15, ty = t >> 4;
    float acc[8][8];
#pragma unroll
    for (int i = 0; i < 8; ++i)
#pragma unroll
        for (int j = 0; j < 8; ++j) acc[i][j] = 0.f;

#pragma unroll
    for (int i = 0; i < 4; ++i) wg[i * 256 + t] = gW2[i * 256 + t];
    if (t < E_) lcnt[t] = 0;

    int stok = t >> 1;
    int skh = (t & 1) * 16;
    int wkk = t >> 3;
    int wh = (t & 7) * 16;

    for (int k0 = 0; k0 < DIN; k0 += 32) {
        const float* xr = x + (size_t)(tokBase + stok) * DIN + k0 + skh;
        float4 a0 = ((const float4*)xr)[0];
        float4 a1 = ((const float4*)xr)[1];
        float4 a2 = ((const float4*)xr)[2];
        float4 a3 = ((const float4*)xr)[3];
        xT[skh + 0][stok] = a0.x;  xT[skh + 1][stok] = a0.y;
        xT[skh + 2][stok] = a0.z;  xT[skh + 3][stok] = a0.w;
        xT[skh + 4][stok] = a1.x;  xT[skh + 5][stok] = a1.y;
        xT[skh + 6][stok] = a1.z;  xT[skh + 7][stok] = a1.w;
        xT[skh + 8][stok] = a2.x;  xT[skh + 9][stok] = a2.y;
        xT[skh + 10][stok] = a2.z; xT[skh + 11][stok] = a2.w;
        xT[skh + 12][stok] = a3.x; xT[skh + 13][stok] = a3.y;
        xT[skh + 14][stok] = a3.z; xT[skh + 15][stok] = a3.w;
        const float* wr = gW1 + (size_t)(k0 + wkk) * GHID + wh;
        *(float4*)&ws[wkk][wh + 0]  = ((const float4*)wr)[0];
        *(float4*)&ws[wkk][wh + 4]  = ((const float4*)wr)[1];
        *(float4*)&ws[wkk][wh + 8]  = ((const float4*)wr)[2];
        *(float4*)&ws[wkk][wh + 12] = ((const float4*)wr)[3];
        __syncthreads();
#pragma unroll 4
        for (int kk = 0; kk < 32; ++kk) {
            f32x4 wv0 = *(const f32x4*)&ws[kk][tx * 8];
            f32x4 wv1 = *(const f32x4*)&ws[kk][tx * 8 + 4];
            f32x4 xv0 = *(const f32x4*)&xT[kk][ty * 8];
            f32x4 xv1 = *(const f32x4*)&xT[kk][ty * 8 + 4];
            float xs[8] = {xv0.x, xv0.y, xv0.z, xv0.w, xv1.x, xv1.y, xv1.z, xv1.w};
            float wsv[8] = {wv0.x, wv0.y, wv0.z, wv0.w, wv1.x, wv1.y, wv1.z, wv1.w};
#pragma unroll
            for (int i = 0; i < 8; ++i)
#pragma unroll
                for (int j = 0; j < 8; ++j) acc[i][j] += xs[i] * wsv[j];
        }
        __syncthreads();
    }
    float4 b0 = *(const float4*)&gb1[tx * 8];
    float4 b1 = *(const float4*)&gb1[tx * 8 + 4];
#pragma unroll
    for (int i = 0; i < 8; ++i) {
        int trow = ty * 8 + i;
        float4 o0, o1;
        o0.x = fmaxf(acc[i][0] + b0.x, 0.f); o0.y = fmaxf(acc[i][1] + b0.y, 0.f);
        o0.z = fmaxf(acc[i][2] + b0.z, 0.f); o0.w = fmaxf(acc[i][3] + b0.w, 0.f);
        o1.x = fmaxf(acc[i][4] + b1.x, 0.f); o1.y = fmaxf(acc[i][5] + b1.y, 0.f);
        o1.z = fmaxf(acc[i][6] + b1.z, 0.f); o1.w = fmaxf(acc[i][7] + b1.w, 0.f);
        *(float4*)&hs[trow][tx * 8] = o0;
        *(float4*)&hs[trow][tx * 8 + 4] = o1;
    }
    __syncthreads();

    // phase 2: logits + top2. 2 lanes per token, 64 hid each.
    int tok = t >> 1, part = t & 1;
    float s[8];
#pragma unroll
    for (int e = 0; e < E_; ++e) s[e] = 0.f;
    const float* hr = &hs[tok][part * 64];
#pragma unroll 4
    for (int jq = 0; jq < 16; ++jq) {
        f32x4 hv = *(const f32x4*)&hr[jq * 4];
#pragma unroll
        for (int j = 0; j < 4; ++j) {
            float h = hv[j];
            int hidx = part * 64 + jq * 4 + j;
            f32x4 w0 = *(const f32x4*)&wg[hidx * 8];
            f32x4 w1 = *(const f32x4*)&wg[hidx * 8 + 4];
            s[0] += h * w0.x; s[1] += h * w0.y; s[2] += h * w0.z; s[3] += h * w0.w;
            s[4] += h * w1.x; s[5] += h * w1.y; s[6] += h * w1.z; s[7] += h * w1.w;
        }
    }
#pragma unroll
    for (int e = 0; e < E_; ++e) s[e] += __shfl_xor(s[e], 1);
    if (part == 0) {
        float l[8];
#pragma unroll
        for (int e = 0; e < E_; ++e) l[e] = s[e] + gb2[e];
        int i1 = 0; float b1v = l[0];
#pragma unroll
        for (int e = 1; e < E_; ++e) if (l[e] > b1v) { b1v = l[e]; i1 = e; }
        int i2 = -1; float b2v = -3.4e38f;
#pragma unroll
        for (int e = 0; e < E_; ++e) if (e != i1 && l[e] > b2v) { b2v = l[e]; i2 = e; }
        float mm = fmaxf(b1v, b2v);
        float p1 = expf(b1v - mm), p2 = expf(b2v - mm);
        float inv = 1.f / (p1 + p2);
        int gtok = tokBase + tok;
        tokE[gtok] = make_int2(i1, i2);
        tokW[gtok] = make_float2(p1 * inv, p2 * inv);
        atomicAdd(&lcnt[i1], 1);
        atomicAdd(&lcnt[i2], 1);
    }
    __syncthreads();
    if (t < E_) atomicAdd(&cnt[t * CNT_STRIDE], lcnt[t]);
}

// ---------- prefix offsets, tile work table, aux outputs (parallel fill) ----------
__global__ void k_route_setup(const int* __restrict__ cnt, int* __restrict__ offs,
                              int* __restrict__ fill, int2* __restrict__ tab,
                              int* __restrict__ NT, float* __restrict__ outTail) {
    int t = threadIdx.x;   // 64 threads
    int c[E_], nt[E_];
#pragma unroll
    for (int e = 0; e < E_; ++e) {
        c[e] = cnt[e * CNT_STRIDE];
        nt[e] = (c[e] + 127) >> 7;
    }
    if (t == 0) {
        int off = 0, ntp = 0;
        float bl = 0.f;
#pragma unroll
        for (int e = 0; e < E_; ++e) {
            offs[e] = off; off += c[e];
            fill[e] = 0;
            ntp += nt[e];
            float u = (float)c[e] / 32768.f;
            outTail[8388609 + e] = u;
            float dd = u - 0.125f;
            bl += dd * dd;
        }
        outTail[8388608] = bl * (0.01f / 8.f);
        *NT = ntp;
    }
    int maxnt = 0;
#pragma unroll
    for (int e = 0; e < E_; ++e) maxnt = max(maxnt, nt[e]);
    for (int k = t; k < maxnt; k += 64) {
        int p = 0;
#pragma unroll
        for (int e = 0; e < E_; ++e) p += min(nt[e], k);
#pragma unroll
        for (int e = 0; e < E_; ++e) {
            if (k < nt[e]) {
                tab[p] = make_int2(e, k);
                ++p;
            }
        }
    }
}

// ---------- gather: assign rows, record token/weight + tokRow, copy x to bf16 ----------
__global__ __launch_bounds__(256) void k_gather(
    const float* __restrict__ x, const int2* __restrict__ tokE,
    const float2* __restrict__ tokW, const int* __restrict__ offs,
    int* __restrict__ fill, int* __restrict__ rowTok, float* __restrict__ rowW,
    int2* __restrict__ tokRow, unsigned short* __restrict__ xg) {
    __shared__ int lc[E_], lbase[E_], lfill[E_];
    __shared__ int srow[512];
    int t = threadIdx.x;
    int tokBase = blockIdx.x * 256;
    if (t < E_) { lc[t] = 0; lfill[t] = 0; }
    __syncthreads();
    for (int s = t; s < 512; s += 256) {
        int token = tokBase + (s >> 1);
        int2 ee = tokE[token];
        int e = (s & 1) ? ee.y : ee.x;
        atomicAdd(&lc[e], 1);
    }
    __syncthreads();
    if (t < E_) lbase[t] = atomicAdd(&fill[t], lc[t]);
    __syncthreads();
    for (int s = t; s < 512; s += 256) {
        int token = tokBase + (s >> 1);
        int2 ee = tokE[token];
        float2 wv = tokW[token];
        int e; float w;
        if (s & 1) { e = ee.y; w = wv.y; } else { e = ee.x; w = wv.x; }
        int r = atomicAdd(&lfill[e], 1);
        int row = offs[e] + lbase[e] + r;
        srow[s] = row;
        rowTok[row] = token;
        rowW[row] = w;
        ((int*)&tokRow[token])[s & 1] = row;
    }
    __syncthreads();
    int wid = t >> 6, lane = t & 63;
    for (int s = wid; s < 512; s += 4) {
        int row = srow[s];
        int token = tokBase + (s >> 1);
        float4 v = ((const float4*)x)[(size_t)token * 64 + lane];
        ushort4 o;
        o.x = f2bf(v.x); o.y = f2bf(v.y); o.z = f2bf(v.z); o.w = f2bf(v.w);
        ((ushort4*)xg)[(size_t)row * 64 + lane] = o;
    }
}

// ---------- grouped GEMM, 128x128 tile, 8 waves, BK=32, 3-buf counted-vmcnt ----------
// R14/R16-verified config (gemm2 62us, occ 50%, conflicts 0). T4 counted vmcnt:
// 3 LDS buffers (48KB), prefetch 2 ahead, steady-state s_waitcnt vmcnt(2)
// -> s_barrier -> stage(s+2) -> ds_read -> MFMA.
// + T5: s_setprio(1) around the MFMA cluster — the counted-vmcnt schedule gives
// waves role diversity (load-issuing vs MFMA-entering) so priority arbitration
// pays (m218b: +21-25% on counted-vmcnt schedules; null only on lockstep drains).
// LDS chunk-XOR swizzle (conflicts=0). XCD remap pins experts to XCDs.
// mode 0: Hout = relu(acc+bias) bf16
// mode 1: outF[row][col] = acc + bias (plain fp32 store; combine applies weights)
template <int NCT>
__global__ __launch_bounds__(512, 4) void k_gemm(
    const unsigned short* __restrict__ A, const unsigned short* __restrict__ BT,
    const float* __restrict__ bias, const int* __restrict__ offs,
    const int* __restrict__ cnt, const int2* __restrict__ tab,
    const int* __restrict__ NT, int N, int K, int mode,
    unsigned short* __restrict__ Hout, float* __restrict__ outF,
    const int* __restrict__ rowTok, const float* __restrict__ rowW) {
    __shared__ __align__(16) unsigned short As[3][128 * 32];  // 3 x 8 KB
    __shared__ __align__(16) unsigned short Bs[3][128 * 32];  // 3 x 8 KB

    unsigned flat = blockIdx.x + (unsigned)NCT * blockIdx.y;
    unsigned xcd = flat % 8u;
    unsigned q = flat / 8u;
    unsigned ct = q % (unsigned)NCT;
    unsigned tIdx = (q / (unsigned)NCT) * 8u + xcd;

    if (tIdx >= (unsigned)*NT || tIdx >= (unsigned)TABCAP) return;
    int2 ent = tab[tIdx];
    int e = ent.x, rt = ent.y;
    int cntE = cnt[e * CNT_STRIDE];
    int rowStart = offs[e] + rt * 128;
    int valid = cntE - rt * 128;
    if (valid > 128) valid = 128;

    int t = threadIdx.x;
    int lane = t & 63, wid = t >> 6;          // 8 waves
    int quad = lane >> 4, l15 = lane & 15;
    int waveM = wid >> 2, waveN = wid & 3;    // 2M x 4N: wave owns 64 rows x 32 cols

    const unsigned short* Ablk = A + (size_t)rowStart * K;
    const unsigned short* Bblk = BT + ((size_t)e * N + (size_t)ct * 128) * K;

    int srow = t >> 2, skc = t & 3;
    int skcs = skc ^ ((srow >> 1) & 3);
    int ar = min(srow, valid - 1);
    const unsigned short* ga = Ablk + (size_t)ar * K + skcs * 8;
    const unsigned short* gb = Bblk + (size_t)srow * K + skcs * 8;
    int la = wid * 512;

    auto stage = [&](int b, int kt) {
        gload_lds16(ga + kt, &As[b][la]);
        gload_lds16(gb + kt, &Bs[b][la]);
    };

    const f32x4 zero = {0.f, 0.f, 0.f, 0.f};
    f32x4 acc[4][2];
#pragma unroll
    for (int i = 0; i < 4; ++i)
#pragma unroll
        for (int j = 0; j < 2; ++j) acc[i][j] = zero;

    int xq = quad ^ ((l15 >> 1) & 3);   // swizzled read chunk
    int nst = K >> 5;                    // 8 or 16
    stage(0, 0);
    stage(1, 32);
    int bs = 0;
    for (int s = 0; s < nst; ++s) {
        if (s + 1 < nst) {
            asm volatile("s_waitcnt vmcnt(2)" ::: "memory");
        } else {
            asm volatile("s_waitcnt vmcnt(0)" ::: "memory");
        }
        __builtin_amdgcn_s_barrier();
        asm volatile("" ::: "memory");
        if (s + 2 < nst) {
            int b2 = bs + 2; if (b2 >= 3) b2 -= 3;
            stage(b2, (s + 2) << 5);
        }
        const unsigned short* Ab = As[bs];
        const unsigned short* Bb = Bs[bs];
        bf16x8 af[4], bf[2];
#pragma unroll
        for (int i = 0; i < 4; ++i)
            af[i] = *(const bf16x8*)&Ab[(waveM * 64 + i * 16 + l15) * 32 + xq * 8];
#pragma unroll
        for (int j = 0; j < 2; ++j)
            bf[j] = *(const bf16x8*)&Bb[(waveN * 32 + j * 16 + l15) * 32 + xq * 8];
        __builtin_amdgcn_s_setprio(1);
#pragma unroll
        for (int i = 0; i < 4; ++i)
#pragma unroll
            for (int j = 0; j < 2; ++j)
                acc[i][j] = __builtin_amdgcn_mfma_f32_16x16x32_bf16(af[i], bf[j], acc[i][j], 0, 0, 0);
        __builtin_amdgcn_s_setprio(0);
        ++bs; if (bs == 3) bs = 0;
    }

    const float* be = bias + (size_t)e * N;
    if (mode == 0) {
#pragma unroll
        for (int i = 0; i < 4; ++i) {
#pragma unroll
            for (int r = 0; r < 4; ++r) {
                int rl = waveM * 64 + i * 16 + quad * 4 + r;
                if (rl < valid) {
                    size_t rowOff = (size_t)(rowStart + rl) * N;
#pragma unroll
                    for (int j = 0; j < 2; ++j) {
                        int col = (int)ct * 128 + waveN * 32 + j * 16 + l15;
                        float v = acc[i][j][r] + be[col];
                        Hout[rowOff + col] = f2bf(fmaxf(v, 0.f));
                    }
                }
            }
        }
    } else {
#pragma unroll
        for (int i = 0; i < 4; ++i) {
#pragma unroll
            for (int r = 0; r < 4; ++r) {
                int rl = waveM * 64 + i * 16 + quad * 4 + r;
                if (rl < valid) {
                    float* yrow = outF + (size_t)(rowStart + rl) * N;
#pragma unroll
                    for (int j = 0; j < 2; ++j) {
                        int col = (int)ct * 128 + waveN * 32 + j * 16 + l15;
                        yrow[col] = acc[i][j][r] + be[col];
                    }
                }
            }
        }
    }
}

// ---------- combine: out[tok] = w0*y[row0] + w1*y[row1] ----------
__global__ __launch_bounds__(256) void k_combine(
    const float* __restrict__ y, const int2* __restrict__ tokRow,
    const float* __restrict__ rowW, float* __restrict__ out) {
    int gid = blockIdx.x * 256 + threadIdx.x;   // one float4 per thread
    int tok = gid >> 6;                          // 64 threads per token
    int cg = (gid & 63) << 2;
    int2 rr = tokRow[tok];
    float w0 = rowW[rr.x], w1 = rowW[rr.y];
    float4 a = *(const float4*)&y[(size_t)rr.x * DOUT + cg];
    float4 b = *(const float4*)&y[(size_t)rr.y * DOUT + cg];
    float4 o;
    o.x = w0 * a.x + w1 * b.x;
    o.y = w0 * a.y + w1 * b.y;
    o.z = w0 * a.z + w1 * b.z;
    o.w = w0 * a.w + w1 * b.w;
    *(float4*)&out[(size_t)tok * DOUT + cg] = o;
}

extern "C" void kernel_launch(void* const* d_in, const int* in_sizes, int n_in,
                              void* d_out, int out_size, void* d_ws, size_t ws_size,
                              hipStream_t stream) {
    const float* x   = (const float*)d_in[0];
    const float* gW1 = (const float*)d_in[1];
    const float* gb1 = (const float*)d_in[2];
    const float* gW2 = (const float*)d_in[3];
    const float* gb2 = (const float*)d_in[4];
    const float* We1 = (const float*)d_in[5];
    const float* be1 = (const float*)d_in[6];
    const float* We2 = (const float*)d_in[7];
    const float* be2 = (const float*)d_in[8];
    const float* We3 = (const float*)d_in[9];
    const float* be3 = (const float*)d_in[10];
    float* out = (float*)d_out;

    uint8_t* ws = (uint8_t*)d_ws;
    size_t off = 0;
    auto alloc = [&](size_t bytes) -> void* {
        void* p = ws + off;
        off += (bytes + 255) & ~(size_t)255;
        return p;
    };
    unsigned short* WT1 = (unsigned short*)alloc((size_t)E_ * HID * DIN * 2);   // [E][512][256]
    unsigned short* WT2 = (unsigned short*)alloc((size_t)E_ * HID * HID * 2);   // [E][512][512]
    unsigned short* WT3 = (unsigned short*)alloc((size_t)E_ * DOUT * HID * 2);  // [E][256][512]
    unsigned short* R1  = (unsigned short*)alloc((size_t)NROW * HID * 2);       // xg then h2
    unsigned short* h1  = (unsigned short*)alloc((size_t)NROW * HID * 2);       // h1 then y (fp32)
    int2*   tokE   = (int2*)alloc((size_t)NTOK * 8);
    float2* tokW   = (float2*)alloc((size_t)NTOK * 8);
    int*    rowTok = (int*)alloc((size_t)NROW * 4);
    float*  rowW   = (float*)alloc((size_t)NROW * 4);
    int2*   tokRow = (int2*)alloc((size_t)NTOK * 8);
    int*    cnt    = (int*)alloc(E_ * CNT_STRIDE * 4);
    int*    offs   = (int*)alloc(256);
    int*    fill   = (int*)alloc(256);
    int*    NT     = (int*)alloc(256);
    int2*   tab    = (int2*)alloc(TABCAP * 8);
    unsigned short* xg = R1;   // [NROW][256] bf16 (dead after gemm1)
    unsigned short* h2 = R1;   // [NROW][512] bf16 (written by gemm2)
    float* y = (float*)h1;     // [NROW][256] fp32 (h1 dead after gemm2)

    hipMemsetAsync(cnt, 0, E_ * CNT_STRIDE * 4, stream);

    k_transpose_all<<<1024, 256, 0, stream>>>(We1, We2, We3, WT1, WT2, WT3);

    k_gate<<<NTOK / 128, 256, 0, stream>>>(x, gW1, gb1, gW2, gb2, tokE, tokW, cnt);
    k_route_setup<<<1, 64, 0, stream>>>(cnt, offs, fill, tab, NT, out);
    k_gather<<<NTOK / 256, 256, 0, stream>>>(x, tokE, tokW, offs, fill, rowTok, rowW,
                                             tokRow, xg);

    k_gemm<4><<<dim3(4, TABCAP), 512, 0, stream>>>(xg, WT1, be1, offs, cnt, tab, NT,
                                                   HID, DIN, 0, h1, nullptr, rowTok, rowW);
    k_gemm<4><<<dim3(4, TABCAP), 512, 0, stream>>>(h1, WT2, be2, offs, cnt, tab, NT,
                                                   HID, HID, 0, h2, nullptr, rowTok, rowW);
    k_gemm<2><<<dim3(2, TABCAP), 512, 0, stream>>>(h2, WT3, be3, offs, cnt, tab, NT,
                                                   DOUT, HID, 1, nullptr, y, rowTok, rowW);
    k_combine<<<NTOK * DOUT / 4 / 256, 256, 0, stream>>>(y, tokRow, rowW, out);
}